// Round 18
// baseline (197.439 us; speedup 1.0000x reference)
//
#include <hip/hip_runtime.h>
#include <hip/hip_bf16.h>
#include <math.h>

// Problem constants
#define BB 4
#define CIN 64
#define CH 32
#define NN 4096
#define NQCH 32
#define LOG2E 1.4426950408889634f
#define L2_10K 13.287712379549449f

// ws layout (floats). ws_size PROVEN ~268 MB. NO aliasing. End = 6,456,320 f = 25.8 MiB.
#define Q4_OFF     1024        // 65536  (Q pre-scaled by LOG2E)
#define K4_OFF     66560       // 65536
#define RMAP_OFF   132096      // 16384
#define CMAPF_OFF  148480      // 16384
#define CPSUM_OFF  164864      // 524288
#define T8_OFF     689152      // 4194304 (32 chunks x 8 per query)
#define G_OFF      4883456     // 524288  (conv1x1(f), no bias, no rmap)
#define XA_OFF     5407744     // 524288
#define XB_OFF     5932032     // 524288

// out layout (f32): x | out | corrected_map
#define OUT_X_OFF   0
#define OUT_O_OFF   524288
#define OUT_CM_OFF  540672

#define CE(x, y) { float ce_lo = fminf(x, y); y = fmaxf(x, y); x = ce_lo; }
#define CED(x, y) { float ce_hi = fmaxf(x, y); y = fminf(x, y); x = ce_hi; }

// Batcher odd-even mergesort, 8 elems ascending (19 CE) — verified r11-17
#define SORT8(a0,a1,a2,a3,a4,a5,a6,a7) \
    CE(a0,a1); CE(a2,a3); CE(a4,a5); CE(a6,a7); \
    CE(a0,a2); CE(a1,a3); CE(a4,a6); CE(a5,a7); \
    CE(a1,a2); CE(a5,a6); \
    CE(a0,a4); CE(a1,a5); CE(a2,a6); CE(a3,a7); \
    CE(a2,a4); CE(a3,a5); \
    CE(a1,a2); CE(a3,a4); CE(a5,a6);

// bitonic -> ascending sort of 8 (12 CE) — verified r11-17
#define BITONIC8(a0,a1,a2,a3,a4,a5,a6,a7) \
    CE(a0,a4); CE(a1,a5); CE(a2,a6); CE(a3,a7); \
    CE(a0,a2); CE(a1,a3); CE(a4,a6); CE(a5,a7); \
    CE(a0,a1); CE(a2,a3); CE(a4,a5); CE(a6,a7);

__device__ __forceinline__ float bilin32(const float* src, int b, int y, int x) {
    float sy = 0.5f * y - 0.25f;
    float sx = 0.5f * x - 0.25f;
    float fy0 = floorf(sy), fx0 = floorf(sx);
    int y0 = (int)fy0, x0 = (int)fx0;
    float fy = sy - fy0, fx = sx - fx0;
    int y0c = min(max(y0, 0), 31), y1c = min(max(y0 + 1, 0), 31);
    int x0c = min(max(x0, 0), 31), x1c = min(max(x0 + 1, 0), 31);
    const float* p = src + b * 1024;
    float v00 = p[y0c * 32 + x0c], v01 = p[y0c * 32 + x1c];
    float v10 = p[y1c * 32 + x0c], v11 = p[y1c * 32 + x1c];
    float v0 = v00 + fx * (v01 - v00);
    float v1 = v10 + fx * (v11 - v10);
    return v0 + fy * (v1 - v0);
}

// K1G: heterogeneous merge (r17 proven). Blocks 0..255: Q/K projection.
// Blocks 256..511: G = conv1x1(f) without bias/rmap.
__global__ __launch_bounds__(512) void k1g(
        const float* __restrict__ fq, const float* __restrict__ fk,
        const float* __restrict__ wq, const float* __restrict__ wk,
        const float* __restrict__ f, const float* __restrict__ w_in,
        float* __restrict__ Q4, float* __restrict__ K4, float* __restrict__ G) {
    __shared__ float wqs[256], wks[256];
    __shared__ float pp[1024];
    __shared__ float red[512][9];
    int tid = threadIdx.x;
    if (blockIdx.x < 256) {
        if (tid < 256) { wqs[tid] = wq[tid]; wks[tid] = wk[tid]; }
        __syncthreads();
        if (tid < 64) {
            float coord = (float)(tid + 1);
            float qy[4] = {0,0,0,0}, qx[4] = {0,0,0,0}, ky[4] = {0,0,0,0}, kx[4] = {0,0,0,0};
            for (int c = 0; c < 32; ++c) {
                float e = (2.0f * (float)(c >> 1)) * (1.0f / 32.0f);
                float ang = coord * exp2f(-e * L2_10K);
                float pr = (c & 1) ? cosf(ang) : sinf(ang);
                #pragma unroll
                for (int m = 0; m < 4; ++m) {
                    qy[m] += wqs[m * 64 + c] * pr;
                    qx[m] += wqs[m * 64 + 32 + c] * pr;
                    ky[m] += wks[m * 64 + c] * pr;
                    kx[m] += wks[m * 64 + 32 + c] * pr;
                }
            }
            #pragma unroll
            for (int m = 0; m < 4; ++m) {
                pp[0 * 256 + m * 64 + tid] = qy[m];
                pp[1 * 256 + m * 64 + tid] = qx[m];
                pp[2 * 256 + m * 64 + tid] = ky[m];
                pp[3 * 256 + m * 64 + tid] = kx[m];
            }
        }
        int qi = tid & 63, g = tid >> 6;
        int gid = blockIdx.x * 64 + qi;
        int b = gid >> 12, hw = gid & 4095;
        const float* fqb = fq + (size_t)b * CIN * NN + hw;
        const float* fkb = fk + (size_t)b * CIN * NN + hw;
        float aq[4] = {0,0,0,0}, ak[4] = {0,0,0,0};
        int c0 = g * 8;
        #pragma unroll
        for (int c = c0; c < c0 + 8; ++c) {
            float vq = fqb[c * NN];
            float vk = fkb[c * NN];
            #pragma unroll
            for (int m = 0; m < 4; ++m) {
                aq[m] += wqs[m * 64 + c] * vq;
                ak[m] += wks[m * 64 + c] * vk;
            }
        }
        #pragma unroll
        for (int m = 0; m < 4; ++m) { red[tid][m] = aq[m]; red[tid][4 + m] = ak[m]; }
        __syncthreads();
        if (tid < 64) {
            int y = hw >> 6, x = hw & 63;
            float q4[4], k4[4];
            #pragma unroll
            for (int m = 0; m < 4; ++m) {
                float sq = 0.0f, sk = 0.0f;
                #pragma unroll
                for (int j = 0; j < 8; ++j) {
                    sq += red[tid + 64 * j][m];
                    sk += red[tid + 64 * j][4 + m];
                }
                q4[m] = LOG2E * (sq + pp[0 * 256 + m * 64 + y] + pp[1 * 256 + m * 64 + x]);
                k4[m] = sk + pp[2 * 256 + m * 64 + y] + pp[3 * 256 + m * 64 + x];
            }
            ((float4*)Q4)[gid] = make_float4(q4[0], q4[1], q4[2], q4[3]);
            ((float4*)K4)[gid] = make_float4(k4[0], k4[1], k4[2], k4[3]);
        }
    } else {
        float* ws_ = pp;   // 1024 floats
        for (int i = tid; i < 1024; i += 512) ws_[i] = w_in[i];
        __syncthreads();
        int gid = (blockIdx.x - 256) * 512 + tid;
        int hw = gid & 4095;
        int og = (gid >> 12) & 7;
        int b  = gid >> 15;
        float acc[4] = {0.0f, 0.0f, 0.0f, 0.0f};
        const float* fb = f + (size_t)b * CH * NN + hw;
        for (int i = 0; i < 32; ++i) {
            float v = fb[i * NN];
            #pragma unroll
            for (int j = 0; j < 4; ++j) acc[j] += ws_[(og * 4 + j) * 32 + i] * v;
        }
        float* go = G + (size_t)b * CH * NN + (og * 4) * NN + hw;
        #pragma unroll
        for (int j = 0; j < 4; ++j) go[j * NN] = acc[j];
    }
}

// K2a: per-(b, q-chunk of 128) column sum of 2^(q'.k), 2 keys/thread.
// grid = B*NQCH*8 = 1024. (r12-r17 proven)
__global__ void k2a_colstats(const float* __restrict__ Q4, const float* __restrict__ K4,
                             float* __restrict__ cpsum) {
    int blk = blockIdx.x;
    int kblk = blk & 7;   blk >>= 3;
    int qch  = blk & 31;  blk >>= 5;
    int b    = blk;
    int tid = threadIdx.x;
    const float4* Qg = (const float4*)Q4 + b * NN + qch * 128;  // uniform base
    int k0 = kblk * 512 + tid;
    float4 kva = ((const float4*)K4)[b * NN + k0];
    float4 kvb = ((const float4*)K4)[b * NN + k0 + 256];
    float sa = 0.0f, sb = 0.0f;
    #pragma unroll 8
    for (int i = 0; i < 128; ++i) {
        float4 q = Qg[i];
        float da = fmaf(q.x, kva.x, fmaf(q.y, kva.y, fmaf(q.z, kva.z, q.w * kva.w)));
        float db = fmaf(q.x, kvb.x, fmaf(q.y, kvb.y, fmaf(q.z, kvb.z, q.w * kvb.w)));
        sa += exp2f(da);
        sb += exp2f(db);
    }
    cpsum[(b * NQCH + qch) * NN + k0] = sa;
    cpsum[(b * NQCH + qch) * NN + k0 + 256] = sb;
}

// K3a v9: 2 QUERIES PER LANE. Wave scores 128 queries x 128-key chunk; key
// scalar-loads amortized over 2 dots, two independent top-8 chains (2x ILP
// on the sort dep-path). k2b fused (c' in LDS). grid = B*8*32 = 1024 x 256.
__global__ __launch_bounds__(256) void k3a_scan(
        const float* __restrict__ Q4, const float* __restrict__ K4,
        const float* __restrict__ cpsum, const float* __restrict__ m_k,
        float* __restrict__ t8) {
    __shared__ float cvs[128];
    int blk = blockIdx.x;
    int kc = blk & 31;  blk >>= 5;
    int g8 = blk & 7;   blk >>= 3;
    int b  = blk;
    int tid = threadIdx.x;
    if (tid < 128) {
        int k = kc * 128 + tid;
        float S = 0.0f;
        #pragma unroll
        for (int j = 0; j < NQCH; ++j) S += cpsum[(b * NQCH + j) * NN + k];
        float mk = bilin32(m_k, b, k >> 6, k & 63);
        cvs[tid] = LOG2E * (mk - 1.0f) - log2f(S);
    }
    __syncthreads();

    int wave = tid >> 6, lane = tid & 63;
    int qbase = (g8 * 4 + wave) * 128;
    int qrowA = qbase + lane;
    int qrowB = qbase + 64 + lane;
    float4 qA = ((const float4*)Q4)[b * NN + qrowA];
    float4 qB = ((const float4*)Q4)[b * NN + qrowB];
    const float4* Kb = (const float4*)K4 + b * NN + kc * 128;   // uniform base

    float tA0=-1e30f,tA1=-1e30f,tA2=-1e30f,tA3=-1e30f;
    float tA4=-1e30f,tA5=-1e30f,tA6=-1e30f,tA7=-1e30f;
    float tB0=-1e30f,tB1=-1e30f,tB2=-1e30f,tB3=-1e30f;
    float tB4=-1e30f,tB5=-1e30f,tB6=-1e30f,tB7=-1e30f;

    for (int i0 = 0; i0 < 128; i0 += 16) {
        float4 cA = *(const float4*)(cvs + i0);
        float4 cB = *(const float4*)(cvs + i0 + 4);
        float4 cC = *(const float4*)(cvs + i0 + 8);
        float4 cD = *(const float4*)(cvs + i0 + 12);
        float4 k0 = Kb[i0 + 0];  float4 k1 = Kb[i0 + 1];
        float4 k2 = Kb[i0 + 2];  float4 k3 = Kb[i0 + 3];
        float4 k4 = Kb[i0 + 4];  float4 k5 = Kb[i0 + 5];
        float4 k6 = Kb[i0 + 6];  float4 k7 = Kb[i0 + 7];
        float4 k8 = Kb[i0 + 8];  float4 k9 = Kb[i0 + 9];
        float4 kA = Kb[i0 + 10]; float4 kB = Kb[i0 + 11];
        float4 kC = Kb[i0 + 12]; float4 kD = Kb[i0 + 13];
        float4 kE = Kb[i0 + 14]; float4 kF = Kb[i0 + 15];
        // query A scores
        float a0 = fmaf(qA.x,k0.x, fmaf(qA.y,k0.y, fmaf(qA.z,k0.z, qA.w*k0.w))) + cA.x;
        float a1 = fmaf(qA.x,k1.x, fmaf(qA.y,k1.y, fmaf(qA.z,k1.z, qA.w*k1.w))) + cA.y;
        float a2 = fmaf(qA.x,k2.x, fmaf(qA.y,k2.y, fmaf(qA.z,k2.z, qA.w*k2.w))) + cA.z;
        float a3 = fmaf(qA.x,k3.x, fmaf(qA.y,k3.y, fmaf(qA.z,k3.z, qA.w*k3.w))) + cA.w;
        float a4 = fmaf(qA.x,k4.x, fmaf(qA.y,k4.y, fmaf(qA.z,k4.z, qA.w*k4.w))) + cB.x;
        float a5 = fmaf(qA.x,k5.x, fmaf(qA.y,k5.y, fmaf(qA.z,k5.z, qA.w*k5.w))) + cB.y;
        float a6 = fmaf(qA.x,k6.x, fmaf(qA.y,k6.y, fmaf(qA.z,k6.z, qA.w*k6.w))) + cB.z;
        float a7 = fmaf(qA.x,k7.x, fmaf(qA.y,k7.y, fmaf(qA.z,k7.z, qA.w*k7.w))) + cB.w;
        float a8 = fmaf(qA.x,k8.x, fmaf(qA.y,k8.y, fmaf(qA.z,k8.z, qA.w*k8.w))) + cC.x;
        float a9 = fmaf(qA.x,k9.x, fmaf(qA.y,k9.y, fmaf(qA.z,k9.z, qA.w*k9.w))) + cC.y;
        float aA = fmaf(qA.x,kA.x, fmaf(qA.y,kA.y, fmaf(qA.z,kA.z, qA.w*kA.w))) + cC.z;
        float aB = fmaf(qA.x,kB.x, fmaf(qA.y,kB.y, fmaf(qA.z,kB.z, qA.w*kB.w))) + cC.w;
        float aC = fmaf(qA.x,kC.x, fmaf(qA.y,kC.y, fmaf(qA.z,kC.z, qA.w*kC.w))) + cD.x;
        float aD = fmaf(qA.x,kD.x, fmaf(qA.y,kD.y, fmaf(qA.z,kD.z, qA.w*kD.w))) + cD.y;
        float aE = fmaf(qA.x,kE.x, fmaf(qA.y,kE.y, fmaf(qA.z,kE.z, qA.w*kE.w))) + cD.z;
        float aF = fmaf(qA.x,kF.x, fmaf(qA.y,kF.y, fmaf(qA.z,kF.z, qA.w*kF.w))) + cD.w;
        float bmA = fmaxf(
            fmaxf(fmaxf(fmaxf(a0,a1), fmaxf(a2,a3)), fmaxf(fmaxf(a4,a5), fmaxf(a6,a7))),
            fmaxf(fmaxf(fmaxf(a8,a9), fmaxf(aA,aB)), fmaxf(fmaxf(aC,aD), fmaxf(aE,aF))));
        if (bmA > tA0) {
            SORT8(a0,a1,a2,a3,a4,a5,a6,a7);
            SORT8(a8,a9,aA,aB,aC,aD,aE,aF);
            float u0 = fmaxf(a0, aF), u1 = fmaxf(a1, aE);
            float u2 = fmaxf(a2, aD), u3 = fmaxf(a3, aC);
            float u4 = fmaxf(a4, aB), u5 = fmaxf(a5, aA);
            float u6 = fmaxf(a6, a9), u7 = fmaxf(a7, a8);
            BITONIC8(u0,u1,u2,u3,u4,u5,u6,u7);
            tA0 = fmaxf(tA0, u7); tA1 = fmaxf(tA1, u6); tA2 = fmaxf(tA2, u5); tA3 = fmaxf(tA3, u4);
            tA4 = fmaxf(tA4, u3); tA5 = fmaxf(tA5, u2); tA6 = fmaxf(tA6, u1); tA7 = fmaxf(tA7, u0);
            BITONIC8(tA0,tA1,tA2,tA3,tA4,tA5,tA6,tA7);
        }
        // query B scores (keys reused from SGPRs)
        float b0 = fmaf(qB.x,k0.x, fmaf(qB.y,k0.y, fmaf(qB.z,k0.z, qB.w*k0.w))) + cA.x;
        float b1 = fmaf(qB.x,k1.x, fmaf(qB.y,k1.y, fmaf(qB.z,k1.z, qB.w*k1.w))) + cA.y;
        float b2 = fmaf(qB.x,k2.x, fmaf(qB.y,k2.y, fmaf(qB.z,k2.z, qB.w*k2.w))) + cA.z;
        float b3 = fmaf(qB.x,k3.x, fmaf(qB.y,k3.y, fmaf(qB.z,k3.z, qB.w*k3.w))) + cA.w;
        float b4 = fmaf(qB.x,k4.x, fmaf(qB.y,k4.y, fmaf(qB.z,k4.z, qB.w*k4.w))) + cB.x;
        float b5 = fmaf(qB.x,k5.x, fmaf(qB.y,k5.y, fmaf(qB.z,k5.z, qB.w*k5.w))) + cB.y;
        float b6 = fmaf(qB.x,k6.x, fmaf(qB.y,k6.y, fmaf(qB.z,k6.z, qB.w*k6.w))) + cB.z;
        float b7 = fmaf(qB.x,k7.x, fmaf(qB.y,k7.y, fmaf(qB.z,k7.z, qB.w*k7.w))) + cB.w;
        float b8 = fmaf(qB.x,k8.x, fmaf(qB.y,k8.y, fmaf(qB.z,k8.z, qB.w*k8.w))) + cC.x;
        float b9 = fmaf(qB.x,k9.x, fmaf(qB.y,k9.y, fmaf(qB.z,k9.z, qB.w*k9.w))) + cC.y;
        float bA = fmaf(qB.x,kA.x, fmaf(qB.y,kA.y, fmaf(qB.z,kA.z, qB.w*kA.w))) + cC.z;
        float bB = fmaf(qB.x,kB.x, fmaf(qB.y,kB.y, fmaf(qB.z,kB.z, qB.w*kB.w))) + cC.w;
        float bC = fmaf(qB.x,kC.x, fmaf(qB.y,kC.y, fmaf(qB.z,kC.z, qB.w*kC.w))) + cD.x;
        float bD = fmaf(qB.x,kD.x, fmaf(qB.y,kD.y, fmaf(qB.z,kD.z, qB.w*kD.w))) + cD.y;
        float bE = fmaf(qB.x,kE.x, fmaf(qB.y,kE.y, fmaf(qB.z,kE.z, qB.w*kE.w))) + cD.z;
        float bF = fmaf(qB.x,kF.x, fmaf(qB.y,kF.y, fmaf(qB.z,kF.z, qB.w*kF.w))) + cD.w;
        float bmB = fmaxf(
            fmaxf(fmaxf(fmaxf(b0,b1), fmaxf(b2,b3)), fmaxf(fmaxf(b4,b5), fmaxf(b6,b7))),
            fmaxf(fmaxf(fmaxf(b8,b9), fmaxf(bA,bB)), fmaxf(fmaxf(bC,bD), fmaxf(bE,bF))));
        if (bmB > tB0) {
            SORT8(b0,b1,b2,b3,b4,b5,b6,b7);
            SORT8(b8,b9,bA,bB,bC,bD,bE,bF);
            float u0 = fmaxf(b0, bF), u1 = fmaxf(b1, bE);
            float u2 = fmaxf(b2, bD), u3 = fmaxf(b3, bC);
            float u4 = fmaxf(b4, bB), u5 = fmaxf(b5, bA);
            float u6 = fmaxf(b6, b9), u7 = fmaxf(b7, b8);
            BITONIC8(u0,u1,u2,u3,u4,u5,u6,u7);
            tB0 = fmaxf(tB0, u7); tB1 = fmaxf(tB1, u6); tB2 = fmaxf(tB2, u5); tB3 = fmaxf(tB3, u4);
            tB4 = fmaxf(tB4, u3); tB5 = fmaxf(tB5, u2); tB6 = fmaxf(tB6, u1); tB7 = fmaxf(tB7, u0);
            BITONIC8(tB0,tB1,tB2,tB3,tB4,tB5,tB6,tB7);
        }
    }
    float* oA = t8 + ((size_t)(b * NN + qrowA)) * 256 + kc * 8;
    oA[0] = tA0; oA[1] = tA1; oA[2] = tA2; oA[3] = tA3;
    oA[4] = tA4; oA[5] = tA5; oA[6] = tA6; oA[7] = tA7;
    float* oB = t8 + ((size_t)(b * NN + qrowB)) * 256 + kc * 8;
    oB[0] = tB0; oB[1] = tB1; oB[2] = tB2; oB[3] = tB3;
    oB[4] = tB4; oB[5] = tB5; oB[6] = tB6; oB[7] = tB7;
}

// K3b: merge 32 chunk-top8s (256 candidates) -> global top-8 -> cm/rmap.
// (r16-r17 proven)
__global__ void k3b_merge(const float* __restrict__ t8, const float* __restrict__ mapin,
                          float* __restrict__ rmap, float* __restrict__ cmapf,
                          float* __restrict__ outp) {
    int tid = threadIdx.x;
    int qid = blockIdx.x * 4 + (tid >> 6);
    int lane = tid & 63;
    const float* p = t8 + (size_t)qid * 256;
    float a = p[lane], bq = p[lane + 64], c = p[lane + 128], d = p[lane + 192];
    CED(a, c); CED(bq, d); CED(a, bq); CED(c, d); CED(bq, c);   // desc: a>=bq>=c>=d
    float sm = 0.0f;
    #pragma unroll
    for (int r = 0; r < 8; ++r) {
        float m = a;
        int ln = lane;
        #pragma unroll
        for (int off = 32; off >= 1; off >>= 1) {
            float om = __shfl_xor(m, off);
            int ol = __shfl_xor(ln, off);
            if (om > m || (om == m && ol < ln)) { m = om; ln = ol; }
        }
        sm += exp2f(m);
        if (lane == ln) { a = bq; bq = c; c = d; d = -1e30f; }
    }
    if (lane == 0) {
        float cmv = sm * 0.125f;
        int b = qid >> 12, hw = qid & 4095;
        float mr = bilin32(mapin, b, hw >> 6, hw & 63);
        float cm = cmv * mr + mr;
        rmap[qid] = 1.0f / (1.0f + __expf(cm));
        cmapf[qid] = cm;
        outp[OUT_CM_OFF + qid] = cm;
    }
}

// K5A: 3x3 conv layer 1 with x1 = rmap*G + b_in fused into tile load. (r17 proven)
__global__ void k5a_conv3(const float* __restrict__ G, const float* __restrict__ rmap,
                          const float* __restrict__ b_in, const float* __restrict__ w,
                          const float* __restrict__ bias, float* __restrict__ xout) {
    __shared__ float tile[32][324];
    __shared__ float wsm[1152];
    __shared__ float bsm[4];
    __shared__ float bin_s[32];
    int blk = blockIdx.x;
    int og = blk & 7;  blk >>= 3;
    int tx = blk & 3;  blk >>= 2;
    int ty = blk & 3;  blk >>= 2;
    int b  = blk;
    int tid = threadIdx.x;
    for (int i = tid; i < 1152; i += 256) wsm[i] = w[og * 1152 + i];
    if (tid < 4) bsm[tid] = bias[og * 4 + tid];
    if (tid < 32) bin_s[tid] = b_in[tid];
    __syncthreads();
    int y0 = ty * 16 - 1, x0 = tx * 16 - 1;
    const float* rb = rmap + b * NN;
    for (int i = tid; i < 32 * 324; i += 256) {
        int c = i / 324, r = i % 324;
        int yy = r / 18, xx = r % 18;
        int gy = y0 + yy, gx = x0 + xx;
        float v = 0.0f;
        if (gy >= 0 && gy < 64 && gx >= 0 && gx < 64) {
            int p = gy * 64 + gx;
            v = fmaf(G[((size_t)b * CH + c) * NN + p], rb[p], bin_s[c]);
        }
        tile[c][r] = v;
    }
    __syncthreads();
    int py = tid >> 4, px = tid & 15;
    float acc[4];
    #pragma unroll
    for (int j = 0; j < 4; ++j) acc[j] = bsm[j];
    for (int i = 0; i < 32; ++i) {
        const float* tr = &tile[i][py * 18 + px];
        float v00 = tr[0],  v01 = tr[1],  v02 = tr[2];
        float v10 = tr[18], v11 = tr[19], v12 = tr[20];
        float v20 = tr[36], v21 = tr[37], v22 = tr[38];
        #pragma unroll
        for (int j = 0; j < 4; ++j) {
            const float* wj = &wsm[j * 288 + i * 9];
            acc[j] += v00 * wj[0] + v01 * wj[1] + v02 * wj[2]
                    + v10 * wj[3] + v11 * wj[4] + v12 * wj[5]
                    + v20 * wj[6] + v21 * wj[7] + v22 * wj[8];
        }
    }
    size_t base = (size_t)b * CH * NN + (size_t)(og * 4) * NN
                + (ty * 16 + py) * 64 + tx * 16 + px;
    #pragma unroll
    for (int j = 0; j < 4; ++j)
        xout[base + j * NN] = fmaxf(acc[j], 0.0f);
}

// K5: 3x3 conv 32->32 (+bias, relu). og-split 8 -> grid 512. (r12-r17 proven)
__global__ void k5_conv3(const float* __restrict__ xin, const float* __restrict__ w,
                         const float* __restrict__ bias, float* __restrict__ xout,
                         float* __restrict__ outx) {
    __shared__ float tile[32][324];
    __shared__ float wsm[1152];
    __shared__ float bsm[4];
    int blk = blockIdx.x;
    int og = blk & 7;  blk >>= 3;
    int tx = blk & 3;  blk >>= 2;
    int ty = blk & 3;  blk >>= 2;
    int b  = blk;
    int tid = threadIdx.x;
    for (int i = tid; i < 1152; i += 256) wsm[i] = w[og * 1152 + i];
    if (tid < 4) bsm[tid] = bias[og * 4 + tid];
    int y0 = ty * 16 - 1, x0 = tx * 16 - 1;
    for (int i = tid; i < 32 * 324; i += 256) {
        int c = i / 324, r = i % 324;
        int yy = r / 18, xx = r % 18;
        int gy = y0 + yy, gx = x0 + xx;
        float v = 0.0f;
        if (gy >= 0 && gy < 64 && gx >= 0 && gx < 64)
            v = xin[((size_t)b * CH + c) * NN + gy * 64 + gx];
        tile[c][r] = v;
    }
    __syncthreads();
    int py = tid >> 4, px = tid & 15;
    float acc[4];
    #pragma unroll
    for (int j = 0; j < 4; ++j) acc[j] = bsm[j];
    for (int i = 0; i < 32; ++i) {
        const float* tr = &tile[i][py * 18 + px];
        float v00 = tr[0],  v01 = tr[1],  v02 = tr[2];
        float v10 = tr[18], v11 = tr[19], v12 = tr[20];
        float v20 = tr[36], v21 = tr[37], v22 = tr[38];
        #pragma unroll
        for (int j = 0; j < 4; ++j) {
            const float* wj = &wsm[j * 288 + i * 9];
            acc[j] += v00 * wj[0] + v01 * wj[1] + v02 * wj[2]
                    + v10 * wj[3] + v11 * wj[4] + v12 * wj[5]
                    + v20 * wj[6] + v21 * wj[7] + v22 * wj[8];
        }
    }
    size_t base = (size_t)b * CH * NN + (size_t)(og * 4) * NN
                + (ty * 16 + py) * 64 + tx * 16 + px;
    #pragma unroll
    for (int j = 0; j < 4; ++j) {
        float r_ = fmaxf(acc[j], 0.0f);
        xout[base + j * NN] = r_;
        if (outx) outx[base + j * NN] = r_;
    }
}

// K6: final 3x3 conv 32->1 + b_out + corrected_map. channel-split 4x8, grid 256
__global__ void k6_convout(const float* __restrict__ xin, const float* __restrict__ w_out,
                           const float* __restrict__ b_out, const float* __restrict__ cmapf,
                           float* __restrict__ outp) {
    __shared__ float wsm[288];
    __shared__ float red[256];
    int tid = threadIdx.x;
    for (int i = tid; i < 288; i += 256) wsm[i] = w_out[i];
    int pxi = tid & 63, g = tid >> 6;
    int gid = blockIdx.x * 64 + pxi;
    int b = gid >> 12, hw = gid & 4095;
    int y = hw >> 6, x = hw & 63;
    __syncthreads();
    float acc = 0.0f;
    int c0 = g * 8;
    for (int i = c0; i < c0 + 8; ++i) {
        const float* xi = xin + ((size_t)b * CH + i) * NN;
        #pragma unroll
        for (int ky = 0; ky < 3; ++ky) {
            int gy = y + ky - 1;
            if (gy < 0 || gy > 63) continue;
            #pragma unroll
            for (int kx = 0; kx < 3; ++kx) {
                int gx = x + kx - 1;
                if (gx < 0 || gx > 63) continue;
                acc += xi[gy * 64 + gx] * wsm[i * 9 + ky * 3 + kx];
            }
        }
    }
    red[tid] = acc;
    __syncthreads();
    if (tid < 64) {
        float a = red[tid] + red[tid + 64] + red[tid + 128] + red[tid + 192]
                + b_out[0] + cmapf[gid];
        outp[OUT_O_OFF + gid] = a;
    }
}

extern "C" void kernel_launch(void* const* d_in, const int* in_sizes, int n_in,
                              void* d_out, int out_size, void* d_ws, size_t ws_size,
                              hipStream_t stream) {
    const float* f     = (const float*)d_in[0];
    const float* mapin = (const float*)d_in[1];
    const float* f_q   = (const float*)d_in[2];
    const float* f_k   = (const float*)d_in[3];
    const float* m_k   = (const float*)d_in[4];
    const float* wq    = (const float*)d_in[5];
    const float* wk    = (const float*)d_in[6];
    const float* w_in  = (const float*)d_in[7];
    const float* b_in  = (const float*)d_in[8];
    const float* w_mid = (const float*)d_in[9];
    const float* b_mid = (const float*)d_in[10];
    const float* w_out = (const float*)d_in[11];
    const float* b_out = (const float*)d_in[12];
    float* outp = (float*)d_out;
    float* ws = (float*)d_ws;

    float* Q4    = ws + Q4_OFF;
    float* K4    = ws + K4_OFF;
    float* RMAP  = ws + RMAP_OFF;
    float* CMAPF = ws + CMAPF_OFF;
    float* CPSUM = ws + CPSUM_OFF;
    float* T8    = ws + T8_OFF;
    float* G     = ws + G_OFF;
    float* XA    = ws + XA_OFF;
    float* XB    = ws + XB_OFF;

    k1g<<<512, 512, 0, stream>>>(f_q, f_k, wq, wk, f, w_in, Q4, K4, G);
    k2a_colstats<<<BB * NQCH * 8, 256, 0, stream>>>(Q4, K4, CPSUM);
    k3a_scan<<<BB * 8 * 32, 256, 0, stream>>>(Q4, K4, CPSUM, m_k, T8);
    k3b_merge<<<BB * NN / 4, 256, 0, stream>>>(T8, mapin, RMAP, CMAPF, outp);
    k5a_conv3<<<512, 256, 0, stream>>>(G, RMAP, b_in, w_mid + 0 * 9216, b_mid + 0 * 32, XB);
    k5_conv3<<<512, 256, 0, stream>>>(XB, w_mid + 1 * 9216, b_mid + 1 * 32, XA, (float*)0);
    k5_conv3<<<512, 256, 0, stream>>>(XA, w_mid + 2 * 9216, b_mid + 2 * 32, XB, outp + OUT_X_OFF);
    k6_convout<<<256, 256, 0, stream>>>(XB, w_out, b_out, CMAPF, outp);
}

// Round 19
// 196.061 us; speedup vs baseline: 1.0070x; 1.0070x over previous
//
#include <hip/hip_runtime.h>
#include <hip/hip_bf16.h>
#include <math.h>

// Problem constants
#define BB 4
#define CIN 64
#define CH 32
#define NN 4096
#define NQCH 32
#define LOG2E 1.4426950408889634f
#define L2_10K 13.287712379549449f

// ws layout (floats). ws_size PROVEN ~268 MB. NO aliasing. End = 6,456,320 f = 25.8 MiB.
#define Q4_OFF     1024        // 65536  (Q pre-scaled by LOG2E)
#define K4_OFF     66560       // 65536
#define RMAP_OFF   132096      // 16384
#define CMAPF_OFF  148480      // 16384
#define CPSUM_OFF  164864      // 524288
#define T8_OFF     689152      // 4194304 (32 chunks x 8 per query)
#define G_OFF      4883456     // 524288  (conv1x1(f), no bias, no rmap)
#define XA_OFF     5407744     // 524288
#define XB_OFF     5932032     // 524288

// out layout (f32): x | out | corrected_map
#define OUT_X_OFF   0
#define OUT_O_OFF   524288
#define OUT_CM_OFF  540672

#define CE(x, y) { float ce_lo = fminf(x, y); y = fmaxf(x, y); x = ce_lo; }
#define CED(x, y) { float ce_hi = fmaxf(x, y); y = fminf(x, y); x = ce_hi; }

// Batcher odd-even mergesort, 8 elems ascending (19 CE) — verified r11-18
#define SORT8(a0,a1,a2,a3,a4,a5,a6,a7) \
    CE(a0,a1); CE(a2,a3); CE(a4,a5); CE(a6,a7); \
    CE(a0,a2); CE(a1,a3); CE(a4,a6); CE(a5,a7); \
    CE(a1,a2); CE(a5,a6); \
    CE(a0,a4); CE(a1,a5); CE(a2,a6); CE(a3,a7); \
    CE(a2,a4); CE(a3,a5); \
    CE(a1,a2); CE(a3,a4); CE(a5,a6);

// bitonic -> ascending sort of 8 (12 CE) — verified r11-18
#define BITONIC8(a0,a1,a2,a3,a4,a5,a6,a7) \
    CE(a0,a4); CE(a1,a5); CE(a2,a6); CE(a3,a7); \
    CE(a0,a2); CE(a1,a3); CE(a4,a6); CE(a5,a7); \
    CE(a0,a1); CE(a2,a3); CE(a4,a5); CE(a6,a7);

__device__ __forceinline__ float bilin32(const float* src, int b, int y, int x) {
    float sy = 0.5f * y - 0.25f;
    float sx = 0.5f * x - 0.25f;
    float fy0 = floorf(sy), fx0 = floorf(sx);
    int y0 = (int)fy0, x0 = (int)fx0;
    float fy = sy - fy0, fx = sx - fx0;
    int y0c = min(max(y0, 0), 31), y1c = min(max(y0 + 1, 0), 31);
    int x0c = min(max(x0, 0), 31), x1c = min(max(x0 + 1, 0), 31);
    const float* p = src + b * 1024;
    float v00 = p[y0c * 32 + x0c], v01 = p[y0c * 32 + x1c];
    float v10 = p[y1c * 32 + x0c], v11 = p[y1c * 32 + x1c];
    float v0 = v00 + fx * (v01 - v00);
    float v1 = v10 + fx * (v11 - v10);
    return v0 + fy * (v1 - v0);
}

// K1G: heterogeneous merge (r17 proven). Blocks 0..255: Q/K projection.
// Blocks 256..511: G = conv1x1(f) without bias/rmap (pointwise identity:
// conv1x1(rmap*f)+b = rmap*conv1x1(f)+b, applied in k5a tile load).
__global__ __launch_bounds__(512) void k1g(
        const float* __restrict__ fq, const float* __restrict__ fk,
        const float* __restrict__ wq, const float* __restrict__ wk,
        const float* __restrict__ f, const float* __restrict__ w_in,
        float* __restrict__ Q4, float* __restrict__ K4, float* __restrict__ G) {
    __shared__ float wqs[256], wks[256];
    __shared__ float pp[1024];
    __shared__ float red[512][9];
    int tid = threadIdx.x;
    if (blockIdx.x < 256) {
        if (tid < 256) { wqs[tid] = wq[tid]; wks[tid] = wk[tid]; }
        __syncthreads();
        if (tid < 64) {
            float coord = (float)(tid + 1);
            float qy[4] = {0,0,0,0}, qx[4] = {0,0,0,0}, ky[4] = {0,0,0,0}, kx[4] = {0,0,0,0};
            for (int c = 0; c < 32; ++c) {
                float e = (2.0f * (float)(c >> 1)) * (1.0f / 32.0f);
                float ang = coord * exp2f(-e * L2_10K);
                float pr = (c & 1) ? cosf(ang) : sinf(ang);
                #pragma unroll
                for (int m = 0; m < 4; ++m) {
                    qy[m] += wqs[m * 64 + c] * pr;
                    qx[m] += wqs[m * 64 + 32 + c] * pr;
                    ky[m] += wks[m * 64 + c] * pr;
                    kx[m] += wks[m * 64 + 32 + c] * pr;
                }
            }
            #pragma unroll
            for (int m = 0; m < 4; ++m) {
                pp[0 * 256 + m * 64 + tid] = qy[m];
                pp[1 * 256 + m * 64 + tid] = qx[m];
                pp[2 * 256 + m * 64 + tid] = ky[m];
                pp[3 * 256 + m * 64 + tid] = kx[m];
            }
        }
        int qi = tid & 63, g = tid >> 6;
        int gid = blockIdx.x * 64 + qi;
        int b = gid >> 12, hw = gid & 4095;
        const float* fqb = fq + (size_t)b * CIN * NN + hw;
        const float* fkb = fk + (size_t)b * CIN * NN + hw;
        float aq[4] = {0,0,0,0}, ak[4] = {0,0,0,0};
        int c0 = g * 8;
        #pragma unroll
        for (int c = c0; c < c0 + 8; ++c) {
            float vq = fqb[c * NN];
            float vk = fkb[c * NN];
            #pragma unroll
            for (int m = 0; m < 4; ++m) {
                aq[m] += wqs[m * 64 + c] * vq;
                ak[m] += wks[m * 64 + c] * vk;
            }
        }
        #pragma unroll
        for (int m = 0; m < 4; ++m) { red[tid][m] = aq[m]; red[tid][4 + m] = ak[m]; }
        __syncthreads();
        if (tid < 64) {
            int y = hw >> 6, x = hw & 63;
            float q4[4], k4[4];
            #pragma unroll
            for (int m = 0; m < 4; ++m) {
                float sq = 0.0f, sk = 0.0f;
                #pragma unroll
                for (int j = 0; j < 8; ++j) {
                    sq += red[tid + 64 * j][m];
                    sk += red[tid + 64 * j][4 + m];
                }
                q4[m] = LOG2E * (sq + pp[0 * 256 + m * 64 + y] + pp[1 * 256 + m * 64 + x]);
                k4[m] = sk + pp[2 * 256 + m * 64 + y] + pp[3 * 256 + m * 64 + x];
            }
            ((float4*)Q4)[gid] = make_float4(q4[0], q4[1], q4[2], q4[3]);
            ((float4*)K4)[gid] = make_float4(k4[0], k4[1], k4[2], k4[3]);
        }
    } else {
        float* ws_ = pp;   // 1024 floats
        for (int i = tid; i < 1024; i += 512) ws_[i] = w_in[i];
        __syncthreads();
        int gid = (blockIdx.x - 256) * 512 + tid;
        int hw = gid & 4095;
        int og = (gid >> 12) & 7;
        int b  = gid >> 15;
        float acc[4] = {0.0f, 0.0f, 0.0f, 0.0f};
        const float* fb = f + (size_t)b * CH * NN + hw;
        for (int i = 0; i < 32; ++i) {
            float v = fb[i * NN];
            #pragma unroll
            for (int j = 0; j < 4; ++j) acc[j] += ws_[(og * 4 + j) * 32 + i] * v;
        }
        float* go = G + (size_t)b * CH * NN + (og * 4) * NN + hw;
        #pragma unroll
        for (int j = 0; j < 4; ++j) go[j * NN] = acc[j];
    }
}

// K2a: per-(b, q-chunk of 128) column sum of 2^(q'.k), 2 keys/thread.
// grid = B*NQCH*8 = 1024. (r12-r18 proven)
__global__ void k2a_colstats(const float* __restrict__ Q4, const float* __restrict__ K4,
                             float* __restrict__ cpsum) {
    int blk = blockIdx.x;
    int kblk = blk & 7;   blk >>= 3;
    int qch  = blk & 31;  blk >>= 5;
    int b    = blk;
    int tid = threadIdx.x;
    const float4* Qg = (const float4*)Q4 + b * NN + qch * 128;  // uniform base
    int k0 = kblk * 512 + tid;
    float4 kva = ((const float4*)K4)[b * NN + k0];
    float4 kvb = ((const float4*)K4)[b * NN + k0 + 256];
    float sa = 0.0f, sb = 0.0f;
    #pragma unroll 8
    for (int i = 0; i < 128; ++i) {
        float4 q = Qg[i];
        float da = fmaf(q.x, kva.x, fmaf(q.y, kva.y, fmaf(q.z, kva.z, q.w * kva.w)));
        float db = fmaf(q.x, kvb.x, fmaf(q.y, kvb.y, fmaf(q.z, kvb.z, q.w * kvb.w)));
        sa += exp2f(da);
        sb += exp2f(db);
    }
    cpsum[(b * NQCH + qch) * NN + k0] = sa;
    cpsum[(b * NQCH + qch) * NN + k0 + 256] = sb;
}

// K3a (r17-exact, measured best): 1 query/lane, 32 chunks of 128 keys,
// batch-16 body, k2b fused (c' in LDS), keys via uniform scalar loads.
// grid = B*16*32 = 2048 x 256 = 8192 waves = 8/SIMD.
__global__ __launch_bounds__(256) void k3a_scan(
        const float* __restrict__ Q4, const float* __restrict__ K4,
        const float* __restrict__ cpsum, const float* __restrict__ m_k,
        float* __restrict__ t8) {
    __shared__ float cvs[128];
    int blk = blockIdx.x;
    int kc = blk & 31;  blk >>= 5;
    int g4 = blk & 15;  blk >>= 4;
    int b  = blk;
    int tid = threadIdx.x;
    if (tid < 128) {
        int k = kc * 128 + tid;
        float S = 0.0f;
        #pragma unroll
        for (int j = 0; j < NQCH; ++j) S += cpsum[(b * NQCH + j) * NN + k];
        float mk = bilin32(m_k, b, k >> 6, k & 63);
        cvs[tid] = LOG2E * (mk - 1.0f) - log2f(S);
    }
    __syncthreads();

    int wave = tid >> 6, lane = tid & 63;
    int qrow = (g4 * 4 + wave) * 64 + lane;
    float4 qv = ((const float4*)Q4)[b * NN + qrow];
    const float4* Kb = (const float4*)K4 + b * NN + kc * 128;   // uniform base

    float t0=-1e30f,t1=-1e30f,t2=-1e30f,t3=-1e30f;
    float t4=-1e30f,t5=-1e30f,t6=-1e30f,t7=-1e30f;   // ascending; t0 = 8th

    for (int i0 = 0; i0 < 128; i0 += 16) {
        float4 cA = *(const float4*)(cvs + i0);
        float4 cB = *(const float4*)(cvs + i0 + 4);
        float4 cC = *(const float4*)(cvs + i0 + 8);
        float4 cD = *(const float4*)(cvs + i0 + 12);
        float4 k0 = Kb[i0 + 0];  float4 k1 = Kb[i0 + 1];
        float4 k2 = Kb[i0 + 2];  float4 k3 = Kb[i0 + 3];
        float4 k4 = Kb[i0 + 4];  float4 k5 = Kb[i0 + 5];
        float4 k6 = Kb[i0 + 6];  float4 k7 = Kb[i0 + 7];
        float s0 = fmaf(qv.x,k0.x, fmaf(qv.y,k0.y, fmaf(qv.z,k0.z, qv.w*k0.w))) + cA.x;
        float s1 = fmaf(qv.x,k1.x, fmaf(qv.y,k1.y, fmaf(qv.z,k1.z, qv.w*k1.w))) + cA.y;
        float s2 = fmaf(qv.x,k2.x, fmaf(qv.y,k2.y, fmaf(qv.z,k2.z, qv.w*k2.w))) + cA.z;
        float s3 = fmaf(qv.x,k3.x, fmaf(qv.y,k3.y, fmaf(qv.z,k3.z, qv.w*k3.w))) + cA.w;
        float s4 = fmaf(qv.x,k4.x, fmaf(qv.y,k4.y, fmaf(qv.z,k4.z, qv.w*k4.w))) + cB.x;
        float s5 = fmaf(qv.x,k5.x, fmaf(qv.y,k5.y, fmaf(qv.z,k5.z, qv.w*k5.w))) + cB.y;
        float s6 = fmaf(qv.x,k6.x, fmaf(qv.y,k6.y, fmaf(qv.z,k6.z, qv.w*k6.w))) + cB.z;
        float s7 = fmaf(qv.x,k7.x, fmaf(qv.y,k7.y, fmaf(qv.z,k7.z, qv.w*k7.w))) + cB.w;
        float4 k8 = Kb[i0 + 8];  float4 k9 = Kb[i0 + 9];
        float4 kA = Kb[i0 + 10]; float4 kB = Kb[i0 + 11];
        float4 kC = Kb[i0 + 12]; float4 kD = Kb[i0 + 13];
        float4 kE = Kb[i0 + 14]; float4 kF = Kb[i0 + 15];
        float s8 = fmaf(qv.x,k8.x, fmaf(qv.y,k8.y, fmaf(qv.z,k8.z, qv.w*k8.w))) + cC.x;
        float s9 = fmaf(qv.x,k9.x, fmaf(qv.y,k9.y, fmaf(qv.z,k9.z, qv.w*k9.w))) + cC.y;
        float sA = fmaf(qv.x,kA.x, fmaf(qv.y,kA.y, fmaf(qv.z,kA.z, qv.w*kA.w))) + cC.z;
        float sB = fmaf(qv.x,kB.x, fmaf(qv.y,kB.y, fmaf(qv.z,kB.z, qv.w*kB.w))) + cC.w;
        float sC = fmaf(qv.x,kC.x, fmaf(qv.y,kC.y, fmaf(qv.z,kC.z, qv.w*kC.w))) + cD.x;
        float sD = fmaf(qv.x,kD.x, fmaf(qv.y,kD.y, fmaf(qv.z,kD.z, qv.w*kD.w))) + cD.y;
        float sE = fmaf(qv.x,kE.x, fmaf(qv.y,kE.y, fmaf(qv.z,kE.z, qv.w*kE.w))) + cD.z;
        float sF = fmaf(qv.x,kF.x, fmaf(qv.y,kF.y, fmaf(qv.z,kF.z, qv.w*kF.w))) + cD.w;
        float bm = fmaxf(
            fmaxf(fmaxf(fmaxf(s0,s1), fmaxf(s2,s3)), fmaxf(fmaxf(s4,s5), fmaxf(s6,s7))),
            fmaxf(fmaxf(fmaxf(s8,s9), fmaxf(sA,sB)), fmaxf(fmaxf(sC,sD), fmaxf(sE,sF))));
        if (bm > t0) {
            SORT8(s0,s1,s2,s3,s4,s5,s6,s7);
            SORT8(s8,s9,sA,sB,sC,sD,sE,sF);
            float u0 = fmaxf(s0, sF), u1 = fmaxf(s1, sE);
            float u2 = fmaxf(s2, sD), u3 = fmaxf(s3, sC);
            float u4 = fmaxf(s4, sB), u5 = fmaxf(s5, sA);
            float u6 = fmaxf(s6, s9), u7 = fmaxf(s7, s8);
            BITONIC8(u0,u1,u2,u3,u4,u5,u6,u7);
            t0 = fmaxf(t0, u7); t1 = fmaxf(t1, u6); t2 = fmaxf(t2, u5); t3 = fmaxf(t3, u4);
            t4 = fmaxf(t4, u3); t5 = fmaxf(t5, u2); t6 = fmaxf(t6, u1); t7 = fmaxf(t7, u0);
            BITONIC8(t0,t1,t2,t3,t4,t5,t6,t7);
        }
    }
    float* o = t8 + ((size_t)(b * NN + qrow)) * 256 + kc * 8;
    o[0] = t0; o[1] = t1; o[2] = t2; o[3] = t3;
    o[4] = t4; o[5] = t5; o[6] = t6; o[7] = t7;
}

// K3b: merge 32 chunk-top8s (256 candidates) -> global top-8 -> cm/rmap.
// (r16-r18 proven)
__global__ void k3b_merge(const float* __restrict__ t8, const float* __restrict__ mapin,
                          float* __restrict__ rmap, float* __restrict__ cmapf,
                          float* __restrict__ outp) {
    int tid = threadIdx.x;
    int qid = blockIdx.x * 4 + (tid >> 6);
    int lane = tid & 63;
    const float* p = t8 + (size_t)qid * 256;
    float a = p[lane], bq = p[lane + 64], c = p[lane + 128], d = p[lane + 192];
    CED(a, c); CED(bq, d); CED(a, bq); CED(c, d); CED(bq, c);   // desc: a>=bq>=c>=d
    float sm = 0.0f;
    #pragma unroll
    for (int r = 0; r < 8; ++r) {
        float m = a;
        int ln = lane;
        #pragma unroll
        for (int off = 32; off >= 1; off >>= 1) {
            float om = __shfl_xor(m, off);
            int ol = __shfl_xor(ln, off);
            if (om > m || (om == m && ol < ln)) { m = om; ln = ol; }
        }
        sm += exp2f(m);
        if (lane == ln) { a = bq; bq = c; c = d; d = -1e30f; }
    }
    if (lane == 0) {
        float cmv = sm * 0.125f;
        int b = qid >> 12, hw = qid & 4095;
        float mr = bilin32(mapin, b, hw >> 6, hw & 63);
        float cm = cmv * mr + mr;
        rmap[qid] = 1.0f / (1.0f + __expf(cm));
        cmapf[qid] = cm;
        outp[OUT_CM_OFF + qid] = cm;
    }
}

// K5A: 3x3 conv layer 1 with x1 = rmap*G + b_in fused into tile load. (r17 proven)
__global__ void k5a_conv3(const float* __restrict__ G, const float* __restrict__ rmap,
                          const float* __restrict__ b_in, const float* __restrict__ w,
                          const float* __restrict__ bias, float* __restrict__ xout) {
    __shared__ float tile[32][324];
    __shared__ float wsm[1152];
    __shared__ float bsm[4];
    __shared__ float bin_s[32];
    int blk = blockIdx.x;
    int og = blk & 7;  blk >>= 3;
    int tx = blk & 3;  blk >>= 2;
    int ty = blk & 3;  blk >>= 2;
    int b  = blk;
    int tid = threadIdx.x;
    for (int i = tid; i < 1152; i += 256) wsm[i] = w[og * 1152 + i];
    if (tid < 4) bsm[tid] = bias[og * 4 + tid];
    if (tid < 32) bin_s[tid] = b_in[tid];
    __syncthreads();
    int y0 = ty * 16 - 1, x0 = tx * 16 - 1;
    const float* rb = rmap + b * NN;
    for (int i = tid; i < 32 * 324; i += 256) {
        int c = i / 324, r = i % 324;
        int yy = r / 18, xx = r % 18;
        int gy = y0 + yy, gx = x0 + xx;
        float v = 0.0f;
        if (gy >= 0 && gy < 64 && gx >= 0 && gx < 64) {
            int p = gy * 64 + gx;
            v = fmaf(G[((size_t)b * CH + c) * NN + p], rb[p], bin_s[c]);
        }
        tile[c][r] = v;
    }
    __syncthreads();
    int py = tid >> 4, px = tid & 15;
    float acc[4];
    #pragma unroll
    for (int j = 0; j < 4; ++j) acc[j] = bsm[j];
    for (int i = 0; i < 32; ++i) {
        const float* tr = &tile[i][py * 18 + px];
        float v00 = tr[0],  v01 = tr[1],  v02 = tr[2];
        float v10 = tr[18], v11 = tr[19], v12 = tr[20];
        float v20 = tr[36], v21 = tr[37], v22 = tr[38];
        #pragma unroll
        for (int j = 0; j < 4; ++j) {
            const float* wj = &wsm[j * 288 + i * 9];
            acc[j] += v00 * wj[0] + v01 * wj[1] + v02 * wj[2]
                    + v10 * wj[3] + v11 * wj[4] + v12 * wj[5]
                    + v20 * wj[6] + v21 * wj[7] + v22 * wj[8];
        }
    }
    size_t base = (size_t)b * CH * NN + (size_t)(og * 4) * NN
                + (ty * 16 + py) * 64 + tx * 16 + px;
    #pragma unroll
    for (int j = 0; j < 4; ++j)
        xout[base + j * NN] = fmaxf(acc[j], 0.0f);
}

// K5: 3x3 conv 32->32 (+bias, relu). og-split 8 -> grid 512. (r12-r18 proven)
__global__ void k5_conv3(const float* __restrict__ xin, const float* __restrict__ w,
                         const float* __restrict__ bias, float* __restrict__ xout,
                         float* __restrict__ outx) {
    __shared__ float tile[32][324];
    __shared__ float wsm[1152];
    __shared__ float bsm[4];
    int blk = blockIdx.x;
    int og = blk & 7;  blk >>= 3;
    int tx = blk & 3;  blk >>= 2;
    int ty = blk & 3;  blk >>= 2;
    int b  = blk;
    int tid = threadIdx.x;
    for (int i = tid; i < 1152; i += 256) wsm[i] = w[og * 1152 + i];
    if (tid < 4) bsm[tid] = bias[og * 4 + tid];
    int y0 = ty * 16 - 1, x0 = tx * 16 - 1;
    for (int i = tid; i < 32 * 324; i += 256) {
        int c = i / 324, r = i % 324;
        int yy = r / 18, xx = r % 18;
        int gy = y0 + yy, gx = x0 + xx;
        float v = 0.0f;
        if (gy >= 0 && gy < 64 && gx >= 0 && gx < 64)
            v = xin[((size_t)b * CH + c) * NN + gy * 64 + gx];
        tile[c][r] = v;
    }
    __syncthreads();
    int py = tid >> 4, px = tid & 15;
    float acc[4];
    #pragma unroll
    for (int j = 0; j < 4; ++j) acc[j] = bsm[j];
    for (int i = 0; i < 32; ++i) {
        const float* tr = &tile[i][py * 18 + px];
        float v00 = tr[0],  v01 = tr[1],  v02 = tr[2];
        float v10 = tr[18], v11 = tr[19], v12 = tr[20];
        float v20 = tr[36], v21 = tr[37], v22 = tr[38];
        #pragma unroll
        for (int j = 0; j < 4; ++j) {
            const float* wj = &wsm[j * 288 + i * 9];
            acc[j] += v00 * wj[0] + v01 * wj[1] + v02 * wj[2]
                    + v10 * wj[3] + v11 * wj[4] + v12 * wj[5]
                    + v20 * wj[6] + v21 * wj[7] + v22 * wj[8];
        }
    }
    size_t base = (size_t)b * CH * NN + (size_t)(og * 4) * NN
                + (ty * 16 + py) * 64 + tx * 16 + px;
    #pragma unroll
    for (int j = 0; j < 4; ++j) {
        float r_ = fmaxf(acc[j], 0.0f);
        xout[base + j * NN] = r_;
        if (outx) outx[base + j * NN] = r_;
    }
}

// K6: final 3x3 conv 32->1 + b_out + corrected_map. channel-split 4x8, grid 256
__global__ void k6_convout(const float* __restrict__ xin, const float* __restrict__ w_out,
                           const float* __restrict__ b_out, const float* __restrict__ cmapf,
                           float* __restrict__ outp) {
    __shared__ float wsm[288];
    __shared__ float red[256];
    int tid = threadIdx.x;
    for (int i = tid; i < 288; i += 256) wsm[i] = w_out[i];
    int pxi = tid & 63, g = tid >> 6;
    int gid = blockIdx.x * 64 + pxi;
    int b = gid >> 12, hw = gid & 4095;
    int y = hw >> 6, x = hw & 63;
    __syncthreads();
    float acc = 0.0f;
    int c0 = g * 8;
    for (int i = c0; i < c0 + 8; ++i) {
        const float* xi = xin + ((size_t)b * CH + i) * NN;
        #pragma unroll
        for (int ky = 0; ky < 3; ++ky) {
            int gy = y + ky - 1;
            if (gy < 0 || gy > 63) continue;
            #pragma unroll
            for (int kx = 0; kx < 3; ++kx) {
                int gx = x + kx - 1;
                if (gx < 0 || gx > 63) continue;
                acc += xi[gy * 64 + gx] * wsm[i * 9 + ky * 3 + kx];
            }
        }
    }
    red[tid] = acc;
    __syncthreads();
    if (tid < 64) {
        float a = red[tid] + red[tid + 64] + red[tid + 128] + red[tid + 192]
                + b_out[0] + cmapf[gid];
        outp[OUT_O_OFF + gid] = a;
    }
}

extern "C" void kernel_launch(void* const* d_in, const int* in_sizes, int n_in,
                              void* d_out, int out_size, void* d_ws, size_t ws_size,
                              hipStream_t stream) {
    const float* f     = (const float*)d_in[0];
    const float* mapin = (const float*)d_in[1];
    const float* f_q   = (const float*)d_in[2];
    const float* f_k   = (const float*)d_in[3];
    const float* m_k   = (const float*)d_in[4];
    const float* wq    = (const float*)d_in[5];
    const float* wk    = (const float*)d_in[6];
    const float* w_in  = (const float*)d_in[7];
    const float* b_in  = (const float*)d_in[8];
    const float* w_mid = (const float*)d_in[9];
    const float* b_mid = (const float*)d_in[10];
    const float* w_out = (const float*)d_in[11];
    const float* b_out = (const float*)d_in[12];
    float* outp = (float*)d_out;
    float* ws = (float*)d_ws;

    float* Q4    = ws + Q4_OFF;
    float* K4    = ws + K4_OFF;
    float* RMAP  = ws + RMAP_OFF;
    float* CMAPF = ws + CMAPF_OFF;
    float* CPSUM = ws + CPSUM_OFF;
    float* T8    = ws + T8_OFF;
    float* G     = ws + G_OFF;
    float* XA    = ws + XA_OFF;
    float* XB    = ws + XB_OFF;

    k1g<<<512, 512, 0, stream>>>(f_q, f_k, wq, wk, f, w_in, Q4, K4, G);
    k2a_colstats<<<BB * NQCH * 8, 256, 0, stream>>>(Q4, K4, CPSUM);
    k3a_scan<<<BB * 16 * 32, 256, 0, stream>>>(Q4, K4, CPSUM, m_k, T8);
    k3b_merge<<<BB * NN / 4, 256, 0, stream>>>(T8, mapin, RMAP, CMAPF, outp);
    k5a_conv3<<<512, 256, 0, stream>>>(G, RMAP, b_in, w_mid + 0 * 9216, b_mid + 0 * 32, XB);
    k5_conv3<<<512, 256, 0, stream>>>(XB, w_mid + 1 * 9216, b_mid + 1 * 32, XA, (float*)0);
    k5_conv3<<<512, 256, 0, stream>>>(XA, w_mid + 2 * 9216, b_mid + 2 * 32, XB, outp + OUT_X_OFF);
    k6_convout<<<256, 256, 0, stream>>>(XB, w_out, b_out, CMAPF, outp);
}